// Round 3
// baseline (264.794 us; speedup 1.0000x reference)
//
#include <hip/hip_runtime.h>

// PETP_Quadratic R6:
//  (a) prep kernel recoalesced: thread = one (frag,lane), 8 lane-coalesced W
//      loads + one 16B half8 store  (was ~16x overfetch, est ~70us -> <10us).
//  (b) main loop: T3+T4 counted-vmcnt pipeline. 3 staging buffers, depth-2
//      prefetch; per chunk: s_waitcnt vmcnt(4) (next chunk's DMAs stay in
//      flight across the barrier), raw s_barrier, issue chunk c+2, compute.
//      vmcnt(0) only at the last chunk; lgkmcnt(0) only once per variant.
//  (c) T5 setprio(1) around the MFMA/af-build cluster.
// Geometry unchanged from R5: 32x32x16 MFMA, lane-owns-position, 3 waves x
// 32 pos, 16 batches/block, grid 1024. LDS 26.1K feat + 3x12K staging = 63K
// -> 2 blocks/CU.

typedef _Float16 half8  __attribute__((ext_vector_type(8)));
typedef float    f32x16 __attribute__((ext_vector_type(16)));

#define NORM 0.022097086912079608f   /* 1/(32*sqrt(2)) */
#define INV_SQRT3 0.5773502691896258f
#define STR 136                       /* feat row stride in halfwords (272B) */

// ---------------- prep: fragment-swizzled f16 weights, per-(t,u) interleave ----
// Ball[((t*32+u)*6 + slot)*512 + lane*8 + j]: lane n = lane&31, kq = lane>>5,
// kh = slot&1, k-channel v = kh*16 + kq*8 + j.
//   slot 0,1: NORM*W0[u][v][n]
//   slot 2,3: NORM*INV_SQRT3*W1[u][v][n]
//   slot 4,5: NORM*(W2[u][v][n] + W3[v][u][n])
// One thread per (frag,lane): for fixed j, lanes read consecutive n -> two
// contiguous 128B segments per load; store is one coalesced half8.
__global__ void prep_kernel(const float* __restrict__ Wa, const float* __restrict__ Wb,
                            const float* __restrict__ Wc, const float* __restrict__ Wd,
                            _Float16* __restrict__ Ball) {
    int idx = blockIdx.x * 256 + threadIdx.x;   // 0..49151
    if (idx >= 49152) return;
    int lane = idx & 63;
    int frag = idx >> 6;          // 0..767, wave-uniform
    int slot = frag % 6;
    int tu   = frag / 6;
    int u = tu & 31, t = tu >> 5;
    int n = lane & 31, kq = lane >> 5;
    int kh = slot & 1, seg = slot >> 1;
    const float* Ws[4] = {Wa, Wb, Wc, Wd};
    const float* W = Ws[t];
    half8 out;
#pragma unroll
    for (int j = 0; j < 8; ++j) {
        int v = kh * 16 + kq * 8 + j;
        float val;
        if (seg == 0)      val = NORM * W[u * 1024 + v * 32 + n];
        else if (seg == 1) val = NORM * INV_SQRT3 * W[32768 + u * 1024 + v * 32 + n];
        else               val = NORM * (W[65536 + u * 1024 + v * 32 + n] +
                                         W[98304 + v * 1024 + u * 32 + n]);
        out[j] = (_Float16)val;
    }
    *(half8*)(Ball + (size_t)frag * 512 + lane * 8) = out;
}

// async global->LDS, 16B per lane. LDS dest = wave-uniform base + lane*16.
__device__ __forceinline__ void gload_lds16(const _Float16* g, _Float16* l) {
    __builtin_amdgcn_global_load_lds(
        (const __attribute__((address_space(1))) unsigned int*)g,
        (__attribute__((address_space(3))) unsigned int*)l, 16, 0, 0);
}

// ---------------- main kernel ----------------
// WG = 192 thr (3 waves) owns 16 batches = 96 positions; wave owns 32 (one M-tile).
// feat[pos][ch] pos-major: ch 0..31 = s, 32+i*32+u = v-component i channel u.
__launch_bounds__(192, 2)
__global__ void petp_main(const float* __restrict__ x,
                          const _Float16* __restrict__ Ball,
                          float* __restrict__ y) {
    __shared__ _Float16 feat[96 * STR];   // 26,112 B
    __shared__ _Float16 Bst[3][6144];     // 3 x 12KB staging (chunk = 2 u-steps)

    const int tid  = threadIdx.x;
    const int wave = tid >> 6;
    const int lane = tid & 63;
    const int mw = lane & 31;   // A row (position in tile) AND C/D col n
    const int q8 = lane >> 5;   // k-half within a K=16 MFMA
    const int wvu = __builtin_amdgcn_readfirstlane(wave);

    f32x16 acc_s;
    f32x16 acc_v[3];
#pragma unroll
    for (int r = 0; r < 16; ++r) {
        acc_s[r] = 0.f; acc_v[0][r] = 0.f; acc_v[1][r] = 0.f; acc_v[2][r] = 0.f;
    }

    const int wg = blockIdx.x;
    const float* xg = x + (size_t)wg * (96 * 128);

#pragma unroll 1
    for (int t = 0; t < 4; ++t) {
        // all prior-variant readers of feat/Bst are done past this barrier
        __builtin_amdgcn_s_barrier();

        const _Float16* Bt = Ball + t * 98304;

        // ---- prologue: issue chunks 0 and 1 (latency hides under feat build) ----
#pragma unroll
        for (int cc = 0; cc < 2; ++cc)
#pragma unroll
            for (int i = 0; i < 4; ++i) {
                int fi = wvu * 4 + i;
                gload_lds16(Bt + (cc * 12 + fi) * 512 + lane * 8, &Bst[cc][fi * 512]);
            }

        // ---- build variant-t features into pos-major LDS ----
#pragma unroll 1
        for (int it = 0; it < 11; ++it) {
            int item = it * 192 + tid;        // 16 batches x 128 channels
            if (item < 2048) {
                int b = item >> 7;
                int c = item & 127;
                const float* bp = xg + b * 768 + c;
                float v00 = bp[0],   v01 = bp[128], v02 = bp[256];
                float v10 = bp[384], v11 = bp[512], v12 = bp[640];
                float rs0 = v00 + v01 + v02, rs1 = v10 + v11 + v12;
                float cs0 = v00 + v10, cs1 = v01 + v11, cs2 = v02 + v12;
                float tot = rs0 + rs1;
                float xv[6] = {v00, v01, v02, v10, v11, v12};
                float rs[2] = {rs0, rs1};
                float cs[3] = {cs0, cs1, cs2};
                int row;
                if (c < 32) row = c;
                else { int cc2 = c - 32; row = 32 + (cc2 % 3) * 32 + (cc2 / 3); }
                _Float16* fp = feat + row;
#pragma unroll
                for (int p6 = 0; p6 < 6; ++p6) {
                    int i = p6 / 3, j = p6 % 3;
                    float xvv = xv[p6];
                    float f;
                    if      (t == 0) f = xvv;
                    else if (t == 1) f = (rs[i] - xvv) * 0.5f;
                    else if (t == 2) f = cs[j] - xvv;
                    else             f = (tot - rs[i] - cs[j] + xvv) * 0.5f;
                    fp[(b * 6 + p6) * STR] = (_Float16)f;
                }
            }
        }

        half8 sl_s[2];       // per-lane A-side k-slices (loaded after barrier)
        half8 sl_v[2][3];
        half8 bcS, bcG0, bcG1, bcG2;
        const _Float16* frow = feat + (wave * 32 + mw) * STR;

        // ---- 16 chunks x 2 u-steps; depth-2 prefetch, counted vmcnt ----
#pragma unroll
        for (int c = 0; c < 16; ++c) {
            // wait: chunk c landed; chunk c+1's 4 DMAs stay in flight.
            if (c == 0)
                asm volatile("s_waitcnt vmcnt(4) lgkmcnt(0)" ::: "memory");
            else if (c < 15)
                asm volatile("s_waitcnt vmcnt(4)" ::: "memory");
            else
                asm volatile("s_waitcnt vmcnt(0)" ::: "memory");
            __builtin_amdgcn_s_barrier();

            if (c < 14) {   // issue chunk c+2 (its buffer was consumed in iter c-1)
#pragma unroll
                for (int i = 0; i < 4; ++i) {
                    int fi = wvu * 4 + i;
                    gload_lds16(Bt + ((c + 2) * 12 + fi) * 512 + lane * 8,
                                &Bst[(c + 2) % 3][fi * 512]);
                }
            }

            if (c == 0) {   // per-lane A-side slices, once per variant
#pragma unroll
                for (int kh = 0; kh < 2; ++kh) {
                    sl_s[kh] = *(const half8*)(frow + kh * 16 + q8 * 8);
#pragma unroll
                    for (int i = 0; i < 3; ++i)
                        sl_v[kh][i] = *(const half8*)(frow + 32 + i * 32 + kh * 16 + q8 * 8);
                }
            }
            if ((c & 3) == 0) {   // broadcast chunk: 8 u-values, register-resident
                const int cku = c >> 2;
                bcS  = *(const half8*)(frow + cku * 8);
                bcG0 = *(const half8*)(frow + 32 + cku * 8);
                bcG1 = *(const half8*)(frow + 64 + cku * 8);
                bcG2 = *(const half8*)(frow + 96 + cku * 8);
            }

            const _Float16* BstC = &Bst[c % 3][0];
            __builtin_amdgcn_s_setprio(1);
#pragma unroll
            for (int ul = 0; ul < 2; ++ul) {
                const int uu = (c * 2 + ul) & 7;   // compile-time (loop unrolled)
                const _Float16* F = BstC + ul * 3072 + lane * 8;
                half8 bA0 = *(const half8*)(F);
                half8 bA1 = *(const half8*)(F + 512);
                half8 bG0 = *(const half8*)(F + 1024);
                half8 bG1 = *(const half8*)(F + 1536);
                half8 bV0 = *(const half8*)(F + 2048);
                half8 bV1 = *(const half8*)(F + 2560);
                _Float16 su = bcS[uu];
                _Float16 g0 = bcG0[uu], g1 = bcG1[uu], g2 = bcG2[uu];

                half8 af;
                // ---- ys: s.s^T ----
                af = sl_s[0] * su;
                acc_s = __builtin_amdgcn_mfma_f32_32x32x16_f16(af, bA0, acc_s, 0, 0, 0);
                af = sl_s[1] * su;
                acc_s = __builtin_amdgcn_mfma_f32_32x32x16_f16(af, bA1, acc_s, 0, 0, 0);
                // ---- ys: Gram(v) ----
                af = sl_v[0][0] * g0 + sl_v[0][1] * g1 + sl_v[0][2] * g2;
                acc_s = __builtin_amdgcn_mfma_f32_32x32x16_f16(af, bG0, acc_s, 0, 0, 0);
                af = sl_v[1][0] * g0 + sl_v[1][1] * g1 + sl_v[1][2] * g2;
                acc_s = __builtin_amdgcn_mfma_f32_32x32x16_f16(af, bG1, acc_s, 0, 0, 0);
                // ---- yv: s[u] v[v,kc], B2 shared across kc ----
#pragma unroll
                for (int kc = 0; kc < 3; ++kc) {
                    half8 af0 = sl_v[0][kc] * su;
                    acc_v[kc] = __builtin_amdgcn_mfma_f32_32x32x16_f16(af0, bV0, acc_v[kc], 0, 0, 0);
                    half8 af1 = sl_v[1][kc] * su;
                    acc_v[kc] = __builtin_amdgcn_mfma_f32_32x32x16_f16(af1, bV1, acc_v[kc], 0, 0, 0);
                }
            }
            __builtin_amdgcn_s_setprio(0);
        }
    }

    // ---- epilogue: 32x32 C/D layout col(n)=lane&31, row=(reg&3)+8*(reg>>2)+4*q8 ----
    float* yg = y + (size_t)wg * (96 * 128);
    const int pb = wave * 32 + q8 * 4;
#pragma unroll
    for (int r = 0; r < 16; ++r) {
        int pos = pb + (r & 3) + 8 * (r >> 2);
        float* yp = yg + pos * 128;
        __builtin_nontemporal_store(acc_s[r], yp + mw);
        __builtin_nontemporal_store(acc_v[0][r], yp + 32 + 3 * mw + 0);
        __builtin_nontemporal_store(acc_v[1][r], yp + 32 + 3 * mw + 1);
        __builtin_nontemporal_store(acc_v[2][r], yp + 32 + 3 * mw + 2);
    }
}

extern "C" void kernel_launch(void* const* d_in, const int* in_sizes, int n_in,
                              void* d_out, int out_size, void* d_ws, size_t ws_size,
                              hipStream_t stream) {
    const float* x  = (const float*)d_in[0];
    const float* Wa = (const float*)d_in[1];
    const float* Wb = (const float*)d_in[2];
    const float* Wc = (const float*)d_in[3];
    const float* Wd = (const float*)d_in[4];
    float* y = (float*)d_out;

    _Float16* Ball = (_Float16*)d_ws;          // 393216 half = 768 KB

    int nbatch = in_sizes[0] / 768;            // 16384
    int nwg = nbatch / 16;                     // 1024

    prep_kernel<<<192, 256, 0, stream>>>(Wa, Wb, Wc, Wd, Ball);
    petp_main<<<nwg, 192, 0, stream>>>(x, Ball, y);
}